// Round 1
// baseline (6460.686 us; speedup 1.0000x reference)
//
#include <hip/hip_runtime.h>
#include <math.h>

#define B_  2048
#define I_  512
#define H_  512
#define L_  32
#define D_  1024
#define O_  512
#define H4_ 2048
#define KC  32

// ---------------------------------------------------------------------------
// Generic GEMM: C[M,N] = A[M,K] @ W[N,K]^T (+ bias[n]).  Row-major everywhere.
// Tile 64x64, 256 threads (16x16), per-thread 4x4, K-chunk KC=32.
// Optional second strided output C2 (for logits [B,L,D] while pre is [B,D]).
// M % 64 == 0, N % 64 == 0, K % KC == 0 for all call sites.
// ---------------------------------------------------------------------------
__global__ __launch_bounds__(256) void gemm_atb(
    const float* __restrict__ A, const float* __restrict__ W,
    const float* __restrict__ bias, float* __restrict__ C, int ldc,
    float* __restrict__ C2, int ldc2,
    int M, int N, int K)
{
    __shared__ __align__(16) float As[KC][68];
    __shared__ __align__(16) float Ws[KC][68];
    const int tx = threadIdx.x & 15, ty = threadIdx.x >> 4;
    const int m0 = blockIdx.y * 64, n0 = blockIdx.x * 64;
    float acc[4][4] = {};

    for (int k0 = 0; k0 < K; k0 += KC) {
        // stage 64 rows x KC floats of A and W, transposed into [k][row]
#pragma unroll
        for (int p = 0; p < 2; ++p) {
            int q = threadIdx.x + 256 * p;      // 0..511
            int r = q >> 3, c = q & 7;          // row 0..63, k-chunk 0..7
            float4 va = *reinterpret_cast<const float4*>(
                &A[(long long)(m0 + r) * K + k0 + c * 4]);
            As[c * 4 + 0][r] = va.x; As[c * 4 + 1][r] = va.y;
            As[c * 4 + 2][r] = va.z; As[c * 4 + 3][r] = va.w;
            float4 vw = *reinterpret_cast<const float4*>(
                &W[(long long)(n0 + r) * K + k0 + c * 4]);
            Ws[c * 4 + 0][r] = vw.x; Ws[c * 4 + 1][r] = vw.y;
            Ws[c * 4 + 2][r] = vw.z; Ws[c * 4 + 3][r] = vw.w;
        }
        __syncthreads();
#pragma unroll
        for (int kk = 0; kk < KC; ++kk) {
            float4 a = *reinterpret_cast<const float4*>(&As[kk][ty * 4]);
            float4 w = *reinterpret_cast<const float4*>(&Ws[kk][tx * 4]);
            float av[4] = {a.x, a.y, a.z, a.w};
            float wv[4] = {w.x, w.y, w.z, w.w};
#pragma unroll
            for (int i = 0; i < 4; ++i)
#pragma unroll
                for (int j = 0; j < 4; ++j)
                    acc[i][j] = fmaf(av[i], wv[j], acc[i][j]);
        }
        __syncthreads();
    }

#pragma unroll
    for (int i = 0; i < 4; ++i) {
        int m = m0 + ty * 4 + i;
        int n = n0 + tx * 4;
        float4 out;
        out.x = acc[i][0]; out.y = acc[i][1]; out.z = acc[i][2]; out.w = acc[i][3];
        if (bias) {
            out.x += bias[n + 0]; out.y += bias[n + 1];
            out.z += bias[n + 2]; out.w += bias[n + 3];
        }
        *reinterpret_cast<float4*>(&C[(long long)m * ldc + n]) = out;
        if (C2)
            *reinterpret_cast<float4*>(&C2[(long long)m * ldc2 + n]) = out;
    }
}

// ---------------------------------------------------------------------------
// Fused LSTM step: gates = hx_in @ Whh^T + (bih+bhh) + P[m_prev[b]] ; then the
// cell update, writing cx (in place) and hx_out.  W columns are gate-
// interleaved so each thread owns all 4 gates of one (b,h) cell.
// Tile: 64 batch rows x 16 h (=64 gate columns). m_prev==nullptr -> inp = 0.
// ---------------------------------------------------------------------------
__global__ __launch_bounds__(256) void lstm_step(
    const float* __restrict__ hx_in, float* __restrict__ cx,
    const float* __restrict__ Whh,               // [4H, H]
    const float* __restrict__ P,                 // [D, 4H] (table) or unused
    const int* __restrict__ m_prev,              // [B] or nullptr
    const float* __restrict__ bih, const float* __restrict__ bhh,
    float* __restrict__ hx_out)
{
    __shared__ __align__(16) float As[KC][68];
    __shared__ __align__(16) float Ws[KC][68];
    __shared__ int ms[64];
    const int tx = threadIdx.x & 15, ty = threadIdx.x >> 4;
    const int m0 = blockIdx.y * 64, h0 = blockIdx.x * 16;
    if (m_prev != nullptr && threadIdx.x < 64)
        ms[threadIdx.x] = m_prev[m0 + threadIdx.x];
    float acc[4][4] = {};

    for (int k0 = 0; k0 < H_; k0 += KC) {
#pragma unroll
        for (int p = 0; p < 2; ++p) {
            int q = threadIdx.x + 256 * p;
            int r = q >> 3, c = q & 7;
            float4 va = *reinterpret_cast<const float4*>(
                &hx_in[(long long)(m0 + r) * H_ + k0 + c * 4]);
            As[c * 4 + 0][r] = va.x; As[c * 4 + 1][r] = va.y;
            As[c * 4 + 2][r] = va.z; As[c * 4 + 3][r] = va.w;
            // column r of the tile = gate (r&3) of h = h0 + (r>>2)
            int wrow = (r & 3) * H_ + h0 + (r >> 2);
            float4 vw = *reinterpret_cast<const float4*>(
                &Whh[(long long)wrow * H_ + k0 + c * 4]);
            Ws[c * 4 + 0][r] = vw.x; Ws[c * 4 + 1][r] = vw.y;
            Ws[c * 4 + 2][r] = vw.z; Ws[c * 4 + 3][r] = vw.w;
        }
        __syncthreads();
#pragma unroll
        for (int kk = 0; kk < KC; ++kk) {
            float4 a = *reinterpret_cast<const float4*>(&As[kk][ty * 4]);
            float4 w = *reinterpret_cast<const float4*>(&Ws[kk][tx * 4]);
            float av[4] = {a.x, a.y, a.z, a.w};
            float wv[4] = {w.x, w.y, w.z, w.w};
#pragma unroll
            for (int i = 0; i < 4; ++i)
#pragma unroll
                for (int j = 0; j < 4; ++j)
                    acc[i][j] = fmaf(av[i], wv[j], acc[i][j]);
        }
        __syncthreads();
    }

    const int h = h0 + tx;   // acc[i][g]: batch m0+ty*4+i, gate g of column h
    float bsum[4];
#pragma unroll
    for (int g = 0; g < 4; ++g) bsum[g] = bih[g * H_ + h] + bhh[g * H_ + h];

#pragma unroll
    for (int i = 0; i < 4; ++i) {
        int b = m0 + ty * 4 + i;
        float g0 = acc[i][0] + bsum[0];
        float g1 = acc[i][1] + bsum[1];
        float g2 = acc[i][2] + bsum[2];
        float g3 = acc[i][3] + bsum[3];
        if (m_prev != nullptr) {
            const float* Pr = P + (long long)ms[ty * 4 + i] * H4_;
            g0 += Pr[0 * H_ + h]; g1 += Pr[1 * H_ + h];
            g2 += Pr[2 * H_ + h]; g3 += Pr[3 * H_ + h];
        }
        float ig = 1.f / (1.f + expf(-g0));
        float fg = 1.f / (1.f + expf(-g1));
        float gg = tanhf(g2);
        float og = 1.f / (1.f + expf(-g3));
        long long off = (long long)b * H_ + h;
        float cnew = fg * cx[off] + ig * gg;
        cx[off] = cnew;
        hx_out[off] = og * tanhf(cnew);
    }
}

// ---------------------------------------------------------------------------
// argmax over D of pre[b,:] + gumbel[l,b,:]; one wave per row.
// Writes messages (float), the one_hot 1.0, and m_all[l*B+b] for the gathers.
// ---------------------------------------------------------------------------
__global__ __launch_bounds__(256) void argmax_step(
    const float* __restrict__ pre,        // [B, D]
    const float* __restrict__ gum,        // gumbel + l*B*D  -> [B, D]
    float* __restrict__ onehot,           // base of one_hot region [B,L,D]
    float* __restrict__ messages,         // base of messages region [B,L]
    int* __restrict__ m_out, int l)
{
    const int wave = threadIdx.x >> 6, lane = threadIdx.x & 63;
    const int b = blockIdx.x * 4 + wave;
    const float* pr = pre + (long long)b * D_;
    const float* gr = gum + (long long)b * D_;
    float best = -INFINITY; int bi = 0;
#pragma unroll
    for (int j = 0; j < D_ / 64; ++j) {
        int idx = lane + j * 64;
        float v = pr[idx] + gr[idx];
        if (v > best) { best = v; bi = idx; }
    }
#pragma unroll
    for (int off = 32; off > 0; off >>= 1) {
        float ov = __shfl_down(best, off);
        int   oi = __shfl_down(bi, off);
        if (ov > best || (ov == best && oi < bi)) { best = ov; bi = oi; }
    }
    if (lane == 0) {
        m_out[b] = bi;
        messages[(long long)b * L_ + l] = (float)bi;
        onehot[((long long)b * L_ + l) * D_ + bi] = 1.0f;
    }
}

// t2h_emb[d, h] = t2h_W[h, d] + t2h_b[h]   (the one-hot "decode" table)
__global__ __launch_bounds__(256) void build_emb(
    const float* __restrict__ t2h_W, const float* __restrict__ t2h_b,
    float* __restrict__ emb)
{
    int idx = blockIdx.x * 256 + threadIdx.x;   // D*H total
    int d = idx >> 9, h = idx & (H_ - 1);
    emb[idx] = t2h_W[(long long)h * D_ + d] + t2h_b[h];
}

// ---------------------------------------------------------------------------
extern "C" void kernel_launch(void* const* d_in, const int* in_sizes, int n_in,
                              void* d_out, int out_size, void* d_ws, size_t ws_size,
                              hipStream_t stream)
{
    (void)in_sizes; (void)n_in; (void)out_size; (void)ws_size;
    const float* x       = (const float*)d_in[0];
    const float* gumbel  = (const float*)d_in[1];
    const float* in_W    = (const float*)d_in[2];
    const float* in_b    = (const float*)d_in[3];
    const float* out_W   = (const float*)d_in[4];
    const float* out_b   = (const float*)d_in[5];
    const float* enc_Wih = (const float*)d_in[6];
    const float* enc_Whh = (const float*)d_in[7];
    const float* enc_bih = (const float*)d_in[8];
    const float* enc_bhh = (const float*)d_in[9];
    const float* dec_Wih = (const float*)d_in[10];
    const float* dec_Whh = (const float*)d_in[11];
    const float* dec_bih = (const float*)d_in[12];
    const float* dec_bhh = (const float*)d_in[13];
    const float* h2t_W   = (const float*)d_in[14];
    const float* h2t_b   = (const float*)d_in[15];
    const float* t2h_W   = (const float*)d_in[16];
    const float* t2h_b   = (const float*)d_in[17];

    float* out      = (float*)d_out;
    float* recon    = out;                                  // [B,O]
    float* onehot   = out + (size_t)B_ * O_;                // [B,L,D]
    float* logits   = onehot + (size_t)B_ * L_ * D_;        // [B,L,D]
    float* messages = logits + (size_t)B_ * L_ * D_;        // [B,L]

    float* ws    = (float*)d_ws;
    float* hxA   = ws;                                      // [B,H]
    float* hxB   = hxA + (size_t)B_ * H_;
    float* cx    = hxB + (size_t)B_ * H_;                   // [B,H]
    float* pre   = cx + (size_t)B_ * H_;                    // [B,D]
    float* emb   = pre + (size_t)B_ * D_;                   // [D,H]
    float* P_enc = emb + (size_t)D_ * H_;                   // [D,4H]
    float* P_dec = P_enc + (size_t)D_ * H4_;                // [D,4H]
    int*   m_all = (int*)(P_dec + (size_t)D_ * H4_);        // [L,B]

    const dim3 blk(256);

    hipMemsetAsync(hxA, 0, (size_t)B_ * H_ * sizeof(float), stream);
    hipMemsetAsync(onehot, 0, (size_t)B_ * L_ * D_ * sizeof(float), stream);

    // cx0 (encoder initial cell state) = x @ in_W^T + in_b
    gemm_atb<<<dim3(H_ / 64, B_ / 64), blk, 0, stream>>>(
        x, in_W, in_b, cx, H_, nullptr, 0, B_, H_, I_);

    // one-hot decode table and the two precomputed gather tables
    build_emb<<<dim3((D_ * H_) / 256), blk, 0, stream>>>(t2h_W, t2h_b, emb);
    gemm_atb<<<dim3(H4_ / 64, D_ / 64), blk, 0, stream>>>(
        emb, enc_Wih, nullptr, P_enc, H4_, nullptr, 0, D_, H4_, H_);
    gemm_atb<<<dim3(H4_ / 64, D_ / 64), blk, 0, stream>>>(
        emb, dec_Wih, nullptr, P_dec, H4_, nullptr, 0, D_, H4_, H_);

    // ---------------- encoder ----------------
    float* hx_cur = hxA;
    float* hx_nxt = hxB;
    for (int l = 0; l < L_; ++l) {
        lstm_step<<<dim3(H_ / 16, B_ / 64), blk, 0, stream>>>(
            hx_cur, cx, enc_Whh, P_enc,
            (l == 0) ? nullptr : (m_all + (size_t)(l - 1) * B_),
            enc_bih, enc_bhh, hx_nxt);
        { float* t = hx_cur; hx_cur = hx_nxt; hx_nxt = t; }
        gemm_atb<<<dim3(D_ / 64, B_ / 64), blk, 0, stream>>>(
            hx_cur, h2t_W, h2t_b, pre, D_,
            logits + (size_t)l * D_, L_ * D_, B_, D_, H_);
        argmax_step<<<dim3(B_ / 4), blk, 0, stream>>>(
            pre, gumbel + (size_t)l * B_ * D_, onehot, messages,
            m_all + (size_t)l * B_, l);
    }

    // ---------------- decoder ----------------
    hipMemsetAsync(hxA, 0, (size_t)B_ * H_ * sizeof(float), stream);
    hipMemsetAsync(cx, 0, (size_t)B_ * H_ * sizeof(float), stream);
    hx_cur = hxA;
    hx_nxt = hxB;
    for (int l = 0; l < L_; ++l) {
        lstm_step<<<dim3(H_ / 16, B_ / 64), blk, 0, stream>>>(
            hx_cur, cx, dec_Whh, P_dec, m_all + (size_t)l * B_,
            dec_bih, dec_bhh, hx_nxt);
        { float* t = hx_cur; hx_cur = hx_nxt; hx_nxt = t; }
    }

    // recon = hx_final @ out_W^T + out_b
    gemm_atb<<<dim3(O_ / 64, B_ / 64), blk, 0, stream>>>(
        hx_cur, out_W, out_b, recon, O_, nullptr, 0, B_, O_, H_);
}